// Round 5
// baseline (1532.204 us; speedup 1.0000x reference)
//
#include <hip/hip_runtime.h>
#include <hip/hip_bf16.h>

typedef __attribute__((ext_vector_type(8))) short bf16x8;
typedef __attribute__((ext_vector_type(4))) float f32x4;

#define NITER 100
#define WS_SCAL  5904
#define WS_AH    8192                 // float offset; then ushort AH[38400], AL[38400]
#define WS_FLOATS (8192 + 19200 + 19200)
#define BUF1 12288                    // byte offset of bounce buffer 1

__device__ __forceinline__ unsigned short f2bf(float x) {  // RNE
  unsigned u = __builtin_bit_cast(unsigned, x);
  u += 0x7fffu + ((u >> 16) & 1u);
  return (unsigned short)(u >> 16);
}
__device__ __forceinline__ float bf2f(unsigned short h) {
  unsigned u = ((unsigned)h) << 16;
  return __builtin_bit_cast(float, u);
}
__device__ __forceinline__ float ubit(unsigned u) { return __builtin_bit_cast(float, u); }
__device__ __forceinline__ unsigned cvt_pk_bf16(float a, float b) {
  unsigned r;
  asm("v_cvt_pk_bf16_f32 %0, %1, %2" : "=v"(r) : "v"(a), "v"(b));
  return r;
}

// ---------------- prep: D (normalized), linv/lambd, A as bf16 hi/lo -> ws ----------------
__global__ __launch_bounds__(256) void prep_kernel(const float* __restrict__ Drr,
                                                   const float* __restrict__ Dth,
                                                   float* __restrict__ ws)
{
  __shared__ float sD[36 * 164];
  __shared__ float sIG[164];
  __shared__ float sRed[256];
  const int tid = (int)threadIdx.x;

  for (int idx = tid; idx < 36 * 164; idx += 256) {
    int t = idx / 164, k = idx - t * 164;
    float v = 0.0f;
    if (k == 0) v = 1.0f;
    else if (k < 161) {
      int km = k - 1, g = km / 40, n = km - g * 40;
      float pw  = powf(Drr[n], (float)t);
      float ang = (float)t * Dth[n];
      float base = ((g & 2) == 0) ? cosf(ang) : sinf(ang);
      v = pw * base;
      if ((g & 1) && (t & 1)) v = -v;
    }
    sD[idx] = v;
  }
  __syncthreads();
  if (tid < 161) {
    float s = 0.0f;
    for (int t = 0; t < 36; ++t) { float d = sD[t * 164 + tid]; s += d * d; }
    float g = sqrtf(s);
    if (g == 0.0f) g = 6.0f;
    sIG[tid] = 1.0f / g;
  }
  __syncthreads();
  for (int idx = tid; idx < 36 * 164; idx += 256) {
    int k = idx % 164;
    if (k < 161) sD[idx] *= sIG[k];
  }
  __syncthreads();
  {  // L = ||DtD||_F = ||D D^T||_F (36x36 gram)
    float local = 0.0f;
    for (int idx = tid; idx < 36 * 36; idx += 256) {
      int t = idx / 36, t2 = idx - t * 36;
      float dot = 0.0f;
      for (int k = 0; k < 161; ++k) dot += sD[t * 164 + k] * sD[t2 * 164 + k];
      local += dot * dot;
    }
    sRed[tid] = local;
  }
  __syncthreads();
  for (int off = 128; off > 0; off >>= 1) {
    if (tid < off) sRed[tid] += sRed[tid + off];
    __syncthreads();
  }
  const float linv = 1.0f / sqrtf(sRed[0]);

  if (blockIdx.x == 0) {
    for (int idx = tid; idx < 36 * 164; idx += 256) ws[idx] = sD[idx];
    if (tid == 0) { ws[WS_SCAL] = linv; ws[WS_SCAL + 1] = 0.01f * linv; }
  }
  unsigned short* AH16 = reinterpret_cast<unsigned short*>(ws + WS_AH);
  unsigned short* AL16 = AH16 + 192 * 200;
  const int ENT = (192 * 200 + (int)gridDim.x - 1) / (int)gridDim.x;
  const int base = (int)blockIdx.x * ENT;
  for (int i = tid; i < ENT; i += 256) {
    int e = base + i;
    if (e >= 192 * 200) break;
    int r = e / 200, j = e - r * 200;
    float a = 0.0f;
    if (r < 161 && j < 161) {
      float dot = 0.0f;
      for (int t = 0; t < 36; ++t) dot += sD[t * 164 + r] * sD[t * 164 + j];
      a = ((r == j) ? 1.0f : 0.0f) - dot * linv;
    }
    unsigned short ah = f2bf(a);
    AH16[e] = ah;
    AL16[e] = f2bf(a - bf2f(ah));
  }
}

// ---------------- fista: 6 waves, 2 tiles/wave, dual column-group pipeline ----------------
// Block = 384 thr = 32 columns (two groups of 16) for all 100 iters.
// Wave w owns row-tiles {2w, 2w+1} (rows 32w..32w+31; tiles 10/11 partly/fully zero-padded).
// Per barrier interval: [ds_read + MFMA chain of group X] overlaps [shrink VALU of group Y].
template <int USE_WS>
__global__ __launch_bounds__(384, 2) void fista_kernel(
    const float* __restrict__ X, const float* __restrict__ Drr,
    const float* __restrict__ Dth, float* __restrict__ out,
    const float* __restrict__ ws)
{
  __shared__ union {
    struct { float sD[36 * 164]; float sIG[164]; float sRed[512]; } su;
    unsigned char bounce[2][2][16 * 384];   // [buf][grp][col*384] = 24576 B
  } sm;
  __shared__ float2 sTT[NITER];             // (tt_k, 1+tt_k)

  float* sD = sm.su.sD;
  const int tid  = (int)threadIdx.x;
  const int lane = tid & 63;
  const int wv   = tid >> 6;     // 0..5
  const int cl   = lane & 15;
  const int hi   = lane >> 4;

  float linv, lambd;
  if constexpr (USE_WS) {
    for (int idx = tid; idx < 36 * 164; idx += 384) sD[idx] = ws[idx];
    linv  = ws[WS_SCAL];
    lambd = ws[WS_SCAL + 1];
  } else {
    for (int idx = tid; idx < 36 * 164; idx += 384) {
      int t = idx / 164, k = idx - t * 164;
      float v = 0.0f;
      if (k == 0) v = 1.0f;
      else if (k < 161) {
        int km = k - 1, g = km / 40, n = km - g * 40;
        float pw  = powf(Drr[n], (float)t);
        float ang = (float)t * Dth[n];
        float base = ((g & 2) == 0) ? cosf(ang) : sinf(ang);
        v = pw * base;
        if ((g & 1) && (t & 1)) v = -v;
      }
      sD[idx] = v;
    }
    __syncthreads();
    if (tid < 161) {
      float s = 0.0f;
      for (int t = 0; t < 36; ++t) { float d = sD[t * 164 + tid]; s += d * d; }
      float g = sqrtf(s);
      if (g == 0.0f) g = 6.0f;
      sm.su.sIG[tid] = 1.0f / g;
    }
    __syncthreads();
    for (int idx = tid; idx < 36 * 164; idx += 384) {
      int k = idx % 164;
      if (k < 161) sD[idx] *= sm.su.sIG[k];
    }
    __syncthreads();
    {
      float local = 0.0f;
      for (int idx = tid; idx < 36 * 36; idx += 384) {
        int t = idx / 36, t2 = idx - t * 36;
        float dot = 0.0f;
        for (int k = 0; k < 161; ++k) dot += sD[t * 164 + k] * sD[t2 * 164 + k];
        local += dot * dot;
      }
      sm.su.sRed[tid] = local;
      if (tid < 128) sm.su.sRed[384 + tid] = 0.0f;
    }
    __syncthreads();
    for (int off = 256; off > 0; off >>= 1) {
      if (tid < off) sm.su.sRed[tid] += sm.su.sRed[tid + off];
      __syncthreads();
    }
    linv  = 1.0f / sqrtf(sm.su.sRed[0]);
    lambd = 0.01f * linv;
  }

  if (tid == 0) {   // tt table (exact reference recurrence)
    float t = 1.0f;
    for (int k = 0; k < NITER; ++k) {
      float tn = 0.5f * (1.0f + sqrtf(1.0f + 4.0f * t * t));
      float tt = (t - 1.0f) / tn;
      sTT[k] = make_float2(tt, 1.0f + tt);
      t = tn;
    }
  }

  // ---------- A fragments (bf16 hi/lo) for tiles {2wv, 2wv+1} ----------
  bf16x8 Ah[2][6], Al[2][6];
  if constexpr (USE_WS) {
    const unsigned short* AH16 = reinterpret_cast<const unsigned short*>(ws + WS_AH);
    const unsigned short* AL16 = AH16 + 192 * 200;
    #pragma unroll
    for (int tau = 0; tau < 2; ++tau) {
      const int r = (2 * wv + tau) * 16 + cl;
      #pragma unroll
      for (int kt = 0; kt < 6; ++kt) {
        Ah[tau][kt] = *reinterpret_cast<const bf16x8*>(AH16 + r * 200 + kt * 32 + hi * 8);
        Al[tau][kt] = *reinterpret_cast<const bf16x8*>(AL16 + r * 200 + kt * 32 + hi * 8);
      }
    }
  } else {
    #pragma unroll
    for (int tau = 0; tau < 2; ++tau) {
      const int r = (2 * wv + tau) * 16 + cl;
      #pragma unroll
      for (int kt = 0; kt < 6; ++kt) {
        const int k0 = kt * 32 + hi * 8;
        float acc8[8];
        #pragma unroll
        for (int j = 0; j < 8; ++j) acc8[j] = 0.0f;
        if (r < 161) {
          for (int t = 0; t < 36; ++t) {
            float vr = sD[t * 164 + r];
            #pragma unroll
            for (int j = 0; j < 8; ++j) acc8[j] += vr * sD[t * 164 + k0 + j];
          }
        }
        bf16x8 vh, vl;
        #pragma unroll
        for (int j = 0; j < 8; ++j) {
          int k = k0 + j;
          float a = 0.0f;
          if (r < 161 && k < 161) {
            a = -acc8[j] * linv;
            if (r == k) a += 1.0f;
          }
          unsigned short h = f2bf(a);
          vh[j] = (short)h;
          vl[j] = (short)f2bf(a - bf2f(h));
        }
        Ah[tau][kt] = vh;
        Al[tau][kt] = vl;
      }
    }
  }

  // ---------- DtY init for both groups ----------
  const int cb = (int)blockIdx.x * 32;
  const int cA = cb + cl, cB = cb + 16 + cl;
  const float* XA = X + (size_t)(cA >> 14) * (36 * 16384) + (cA & 16383);
  const float* XB = X + (size_t)(cB >> 14) * (36 * 16384) + (cB & 16383);

  f32x4 Pa0[2], Pb0[2], xe0[2], Pa1[2], Pb1[2], xe1[2];
  #pragma unroll
  for (int tau = 0; tau < 2; ++tau)
    #pragma unroll
    for (int q = 0; q < 4; ++q) {
      Pa0[tau][q] = 0.0f; Pb0[tau][q] = 0.0f; xe0[tau][q] = 0.0f;
      Pa1[tau][q] = 0.0f; Pb1[tau][q] = 0.0f; xe1[tau][q] = 0.0f;
    }

  for (int t = 0; t < 36; ++t) {
    float yA = XA[(size_t)t * 16384];
    float yB = XB[(size_t)t * 16384];
    #pragma unroll
    for (int tau = 0; tau < 2; ++tau) {
      f32x4 df = *reinterpret_cast<const f32x4*>(sD + t * 164 + (2 * wv + tau) * 16 + hi * 4);
      #pragma unroll
      for (int q = 0; q < 4; ++q) { Pa0[tau][q] += df[q] * yA; Pa1[tau][q] += df[q] * yB; }
    }
  }
  #pragma unroll
  for (int tau = 0; tau < 2; ++tau)
    #pragma unroll
    for (int q = 0; q < 4; ++q) {
      int r = (2 * wv + tau) * 16 + hi * 4 + q;
      Pa0[tau][q] = (r < 161) ? Pa0[tau][q] * linv : 0.0f;
      Pa1[tau][q] = (r < 161) ? Pa1[tau][q] * linv : 0.0f;
    }
  __syncthreads();   // sD dead; union becomes bounce. sTT visible.

  // ---------- swizzled LDS addresses (loop-invariant) ----------
  unsigned char* colb0 = &sm.bounce[0][0][0] + cl * 384;
  unsigned char* colb1 = &sm.bounce[0][1][0] + cl * 384;
  const unsigned swz = (unsigned)((cl & 7) << 4);
  unsigned char* pe0 = colb0 + ((unsigned)(hi * 16) ^ swz);        // even kt: +0,128,256
  unsigned char* po0 = colb0 + ((unsigned)(64 + hi * 16) ^ swz);   // odd  kt: +0,128
  unsigned char* pe1 = colb1 + ((unsigned)(hi * 16) ^ swz);
  unsigned char* po1 = colb1 + ((unsigned)(64 + hi * 16) ^ swz);
  unsigned char* wr0[2];
  unsigned char* wr1[2];
  #pragma unroll
  for (int tau = 0; tau < 2; ++tau) {
    unsigned off = ((unsigned)((2 * wv + tau) * 32 + hi * 8)) ^ swz;
    wr0[tau] = colb0 + off;
    wr1[tau] = colb1 + off;
  }

  // ---------- pipelined FISTA loop ----------
  auto sh = [&](f32x4 (&PC)[2], f32x4 (&PN)[2], f32x4 (&xe)[2], int it,
                unsigned char* (&wr)[2], int boff) {
    float2 tt2 = sTT[it];
    const float ttp = tt2.x, c1 = tt2.y;
    #pragma unroll
    for (int tau = 0; tau < 2; ++tau) {
      float dq_[4];
      #pragma unroll
      for (int q = 0; q < 4; ++q) {
        float u  = c1 * PC[tau][q] - ttp * PN[tau][q];
        float aa = fmaxf(fabsf(u) - lambd, 0.0f);
        float xn = __builtin_copysignf(aa, u);
        dq_[q] = xn - xe[tau][q];
      }
      unsigned w0 = cvt_pk_bf16(dq_[0], dq_[1]);
      unsigned w1 = cvt_pk_bf16(dq_[2], dq_[3]);
      xe[tau][0] += ubit(w0 << 16);
      xe[tau][1] += ubit(w0 & 0xffff0000u);
      xe[tau][2] += ubit(w1 << 16);
      xe[tau][3] += ubit(w1 & 0xffff0000u);
      *reinterpret_cast<uint2*>(wr[tau] + boff) = make_uint2(w0, w1);
    }
  };
  auto mf = [&](f32x4 (&PC)[2], f32x4 (&PN)[2],
                const unsigned char* pe, const unsigned char* po, int boff) {
    bf16x8 bh[6];
    bh[0] = *reinterpret_cast<const bf16x8*>(pe + boff + 0);
    bh[1] = *reinterpret_cast<const bf16x8*>(po + boff + 0);
    bh[2] = *reinterpret_cast<const bf16x8*>(pe + boff + 128);
    bh[3] = *reinterpret_cast<const bf16x8*>(po + boff + 128);
    bh[4] = *reinterpret_cast<const bf16x8*>(pe + boff + 256);
    bh[5] = *reinterpret_cast<const bf16x8*>(po + boff + 256);
    #pragma unroll
    for (int tau = 0; tau < 2; ++tau) {
      f32x4 acc = PC[tau];
      #pragma unroll
      for (int kt = 0; kt < 6; ++kt) {
        acc = __builtin_amdgcn_mfma_f32_16x16x32_bf16(Ah[tau][kt], bh[kt], acc, 0, 0, 0);
        acc = __builtin_amdgcn_mfma_f32_16x16x32_bf16(Al[tau][kt], bh[kt], acc, 0, 0, 0);
      }
      PN[tau] = acc;
    }
  };

  sh(Pa0, Pb0, xe0, 0, wr0, 0);            // g0 it=0 -> buf0
  #pragma unroll 1
  for (int j = 0; j < NITER / 2; ++j) {
    const int it = 2 * j;
    __syncthreads();
    mf(Pa0, Pb0, pe0, po0, 0);     sh(Pa1, Pb1, xe1, it, wr1, 0);
    __syncthreads();
    mf(Pa1, Pb1, pe1, po1, 0);     sh(Pb0, Pa0, xe0, it + 1, wr0, BUF1);
    __syncthreads();
    mf(Pb0, Pa0, pe0, po0, BUF1);  sh(Pb1, Pa1, xe1, it + 1, wr1, BUF1);
    __syncthreads();
    mf(Pb1, Pa1, pe1, po1, BUF1);
    if (j < NITER / 2 - 1) sh(Pa0, Pb0, xe0, it + 2, wr0, 0);
  }

  // ---------- store x (= xe) for both groups ----------
  float* oA = out + (size_t)(cA >> 14) * (161 * 16384) + (cA & 16383);
  float* oB = out + (size_t)(cB >> 14) * (161 * 16384) + (cB & 16383);
  #pragma unroll
  for (int tau = 0; tau < 2; ++tau)
    #pragma unroll
    for (int q = 0; q < 4; ++q) {
      int r = (2 * wv + tau) * 16 + hi * 4 + q;
      if (r < 161) {
        oA[(size_t)r * 16384] = xe0[tau][q];
        oB[(size_t)r * 16384] = xe1[tau][q];
      }
    }
}

extern "C" void kernel_launch(void* const* d_in, const int* in_sizes, int n_in,
                              void* d_out, int out_size, void* d_ws, size_t ws_size,
                              hipStream_t stream) {
  const float* X   = (const float*)d_in[0];
  const float* Drr = (const float*)d_in[1];
  const float* Dth = (const float*)d_in[2];
  float* out = (float*)d_out;
  (void)in_sizes; (void)n_in; (void)out_size;

  if (ws_size >= (size_t)WS_FLOATS * sizeof(float)) {
    float* ws = (float*)d_ws;
    prep_kernel<<<dim3(64), dim3(256), 0, stream>>>(Drr, Dth, ws);
    fista_kernel<1><<<dim3(2048), dim3(384), 0, stream>>>(X, Drr, Dth, out, ws);
  } else {
    fista_kernel<0><<<dim3(2048), dim3(384), 0, stream>>>(X, Drr, Dth, out, nullptr);
  }
}

// Round 6
// 1340.758 us; speedup vs baseline: 1.1428x; 1.1428x over previous
//
#include <hip/hip_runtime.h>
#include <hip/hip_bf16.h>

typedef __attribute__((ext_vector_type(8))) short bf16x8;
typedef __attribute__((ext_vector_type(4))) float f32x4;

#define NITER 100
#define WS_SCAL  5904
#define WS_TT    6016                 // float2[NITER] = 200 floats
#define WS_AH    8192                 // then ushort AH[192*200], AL[192*200]
#define WS_FLOATS (8192 + 19200 + 19200)
#define BUFB 6144                     // bytes per bounce buffer (16 cols * 384)

__device__ __forceinline__ unsigned short f2bf(float x) {  // RNE
  unsigned u = __builtin_bit_cast(unsigned, x);
  u += 0x7fffu + ((u >> 16) & 1u);
  return (unsigned short)(u >> 16);
}
__device__ __forceinline__ float bf2f(unsigned short h) {
  unsigned u = ((unsigned)h) << 16;
  return __builtin_bit_cast(float, u);
}
__device__ __forceinline__ float ubit(unsigned u) { return __builtin_bit_cast(float, u); }
__device__ __forceinline__ unsigned cvt_pk_bf16(float a, float b) {
  unsigned r;
  asm("v_cvt_pk_bf16_f32 %0, %1, %2" : "=v"(r) : "v"(a), "v"(b));
  return r;
}

// ---------------- prep: D, linv/lambd, tt table, A as bf16 hi/lo -> ws ----------------
__global__ __launch_bounds__(256) void prep_kernel(const float* __restrict__ Drr,
                                                   const float* __restrict__ Dth,
                                                   float* __restrict__ ws)
{
  __shared__ float sD[36 * 164];
  __shared__ float sIG[164];
  __shared__ float sRed[256];
  const int tid = (int)threadIdx.x;

  for (int idx = tid; idx < 36 * 164; idx += 256) {
    int t = idx / 164, k = idx - t * 164;
    float v = 0.0f;
    if (k == 0) v = 1.0f;
    else if (k < 161) {
      int km = k - 1, g = km / 40, n = km - g * 40;
      float pw  = powf(Drr[n], (float)t);
      float ang = (float)t * Dth[n];
      float base = ((g & 2) == 0) ? cosf(ang) : sinf(ang);
      v = pw * base;
      if ((g & 1) && (t & 1)) v = -v;
    }
    sD[idx] = v;
  }
  __syncthreads();
  if (tid < 161) {
    float s = 0.0f;
    for (int t = 0; t < 36; ++t) { float d = sD[t * 164 + tid]; s += d * d; }
    float g = sqrtf(s);
    if (g == 0.0f) g = 6.0f;
    sIG[tid] = 1.0f / g;
  }
  __syncthreads();
  for (int idx = tid; idx < 36 * 164; idx += 256) {
    int k = idx % 164;
    if (k < 161) sD[idx] *= sIG[k];
  }
  __syncthreads();
  {  // L = ||DtD||_F = ||D D^T||_F (36x36 gram)
    float local = 0.0f;
    for (int idx = tid; idx < 36 * 36; idx += 256) {
      int t = idx / 36, t2 = idx - t * 36;
      float dot = 0.0f;
      for (int k = 0; k < 161; ++k) dot += sD[t * 164 + k] * sD[t2 * 164 + k];
      local += dot * dot;
    }
    sRed[tid] = local;
  }
  __syncthreads();
  for (int off = 128; off > 0; off >>= 1) {
    if (tid < off) sRed[tid] += sRed[tid + off];
    __syncthreads();
  }
  const float linv = 1.0f / sqrtf(sRed[0]);

  if (blockIdx.x == 0) {
    for (int idx = tid; idx < 36 * 164; idx += 256) ws[idx] = sD[idx];
    if (tid == 0) {
      ws[WS_SCAL] = linv;
      ws[WS_SCAL + 1] = 0.01f * linv;
      float t = 1.0f;                     // tt table (exact reference recurrence)
      for (int k = 0; k < NITER; ++k) {
        float tn = 0.5f * (1.0f + sqrtf(1.0f + 4.0f * t * t));
        float tt = (t - 1.0f) / tn;
        ws[WS_TT + 2 * k]     = tt;
        ws[WS_TT + 2 * k + 1] = 1.0f + tt;
        t = tn;
      }
    }
  }
  unsigned short* AH16 = reinterpret_cast<unsigned short*>(ws + WS_AH);
  unsigned short* AL16 = AH16 + 192 * 200;
  const int ENT = (192 * 200 + (int)gridDim.x - 1) / (int)gridDim.x;
  const int base = (int)blockIdx.x * ENT;
  for (int i = tid; i < ENT; i += 256) {
    int e = base + i;
    if (e >= 192 * 200) break;
    int r = e / 200, j = e - r * 200;
    float a = 0.0f;
    if (r < 161 && j < 161) {
      float dot = 0.0f;
      for (int t = 0; t < 36; ++t) dot += sD[t * 164 + r] * sD[t * 164 + j];
      a = ((r == j) ? 1.0f : 0.0f) - dot * linv;
    }
    unsigned short ah = f2bf(a);
    AH16[e] = ah;
    AL16[e] = f2bf(a - bf2f(ah));
  }
}

// ---------------- fista: 12 waves x 1 row-tile, 16 cols/block, 3 waves/SIMD ----------------
// Wave w owns A rows 16w..16w+15 (uniform; rows>=161 are zero-padded).
// Per-wave regs ~115 (A 48 + P/xe 12 + bh 24 + misc) << 170 budget at 3 waves/EU -> no spill.
template <int USE_WS>
__global__ __launch_bounds__(768, 3) void fista_kernel(
    const float* __restrict__ X, const float* __restrict__ Drr,
    const float* __restrict__ Dth, float* __restrict__ out,
    const float* __restrict__ ws)
{
  __shared__ union {
    struct { float sD[36 * 164]; float sIG[164]; float sRed[768]; } su;
    struct { unsigned char bounce[2][BUFB]; float2 tt[128]; } lp;
  } sm;
  float* sD = sm.su.sD;

  const int tid  = (int)threadIdx.x;
  const int lane = tid & 63;
  const int wv   = tid >> 6;     // 0..11 = owned row-tile
  const int cl   = lane & 15;    // column / A-row-in-tile
  const int hi   = lane >> 4;    // 0..3

  float linv, lambd;
  if constexpr (USE_WS) {
    for (int idx = tid; idx < 36 * 164; idx += 768) sD[idx] = ws[idx];
    linv  = ws[WS_SCAL];
    lambd = ws[WS_SCAL + 1];
    __syncthreads();
  } else {
    // -------- in-block fallback (correctness path) --------
    for (int idx = tid; idx < 36 * 164; idx += 768) {
      int t = idx / 164, k = idx - t * 164;
      float v = 0.0f;
      if (k == 0) v = 1.0f;
      else if (k < 161) {
        int km = k - 1, g = km / 40, n = km - g * 40;
        float pw  = powf(Drr[n], (float)t);
        float ang = (float)t * Dth[n];
        float base = ((g & 2) == 0) ? cosf(ang) : sinf(ang);
        v = pw * base;
        if ((g & 1) && (t & 1)) v = -v;
      }
      sD[idx] = v;
    }
    __syncthreads();
    if (tid < 161) {
      float s = 0.0f;
      for (int t = 0; t < 36; ++t) { float d = sD[t * 164 + tid]; s += d * d; }
      float g = sqrtf(s);
      if (g == 0.0f) g = 6.0f;
      sm.su.sIG[tid] = 1.0f / g;
    }
    __syncthreads();
    for (int idx = tid; idx < 36 * 164; idx += 768) {
      int k = idx % 164;
      if (k < 161) sD[idx] *= sm.su.sIG[k];
    }
    __syncthreads();
    {
      float local = 0.0f;
      for (int idx = tid; idx < 36 * 36; idx += 768) {
        int t = idx / 36, t2 = idx - t * 36;
        float dot = 0.0f;
        for (int k = 0; k < 161; ++k) dot += sD[t * 164 + k] * sD[t2 * 164 + k];
        local += dot * dot;
      }
      sm.su.sRed[tid] = local;
    }
    __syncthreads();
    if (tid < 256) sm.su.sRed[tid] += sm.su.sRed[tid + 256] + sm.su.sRed[tid + 512];
    __syncthreads();
    for (int off = 128; off > 0; off >>= 1) {
      if (tid < off) sm.su.sRed[tid] += sm.su.sRed[tid + off];
      __syncthreads();
    }
    linv  = 1.0f / sqrtf(sm.su.sRed[0]);
    lambd = 0.01f * linv;
  }

  // ---------- A fragments (bf16 hi/lo) for row-tile wv ----------
  bf16x8 Ah[6], Al[6];
  if constexpr (USE_WS) {
    const unsigned short* AH16 = reinterpret_cast<const unsigned short*>(ws + WS_AH);
    const unsigned short* AL16 = AH16 + 192 * 200;
    const int r = wv * 16 + cl;
    #pragma unroll
    for (int kt = 0; kt < 6; ++kt) {
      Ah[kt] = *reinterpret_cast<const bf16x8*>(AH16 + r * 200 + kt * 32 + hi * 8);
      Al[kt] = *reinterpret_cast<const bf16x8*>(AL16 + r * 200 + kt * 32 + hi * 8);
    }
  } else {
    const int r = wv * 16 + cl;
    #pragma unroll
    for (int kt = 0; kt < 6; ++kt) {
      const int k0 = kt * 32 + hi * 8;
      float acc8[8];
      #pragma unroll
      for (int j = 0; j < 8; ++j) acc8[j] = 0.0f;
      if (r < 161) {
        for (int t = 0; t < 36; ++t) {
          float vr = sD[t * 164 + r];
          #pragma unroll
          for (int j = 0; j < 8; ++j) acc8[j] += vr * sD[t * 164 + k0 + j];
        }
      }
      bf16x8 vh, vl;
      #pragma unroll
      for (int j = 0; j < 8; ++j) {
        int k = k0 + j;
        float a = 0.0f;
        if (r < 161 && k < 161) {
          a = -acc8[j] * linv;
          if (r == k) a += 1.0f;
        }
        unsigned short h = f2bf(a);
        vh[j] = (short)h;
        vl[j] = (short)f2bf(a - bf2f(h));
      }
      Ah[kt] = vh;
      Al[kt] = vl;
    }
  }

  // ---------- DtY -> P0 (C/D layout: row = wv*16 + hi*4 + q, col = cl) ----------
  const int c = (int)blockIdx.x * 16 + cl;
  const int b = c >> 14;
  const int p = c & 16383;
  const float* Xc = X + (size_t)b * (36 * 16384) + p;

  f32x4 P0, P1, xe;
  #pragma unroll
  for (int q = 0; q < 4; ++q) { P0[q] = 0.0f; P1[q] = 0.0f; xe[q] = 0.0f; }

  for (int t = 0; t < 36; ++t) {
    float yv = Xc[(size_t)t * 16384];
    f32x4 df = *reinterpret_cast<const f32x4*>(sD + t * 164 + wv * 16 + hi * 4);
    #pragma unroll
    for (int q = 0; q < 4; ++q) P0[q] += df[q] * yv;
  }
  #pragma unroll
  for (int q = 0; q < 4; ++q) {
    int r = wv * 16 + hi * 4 + q;
    P0[q] = (r < 161) ? P0[q] * linv : 0.0f;
  }
  __syncthreads();   // sD dead; union becomes {bounce, tt}

  // ---------- tt table into LDS ----------
  if constexpr (USE_WS) {
    const float2* wt = reinterpret_cast<const float2*>(ws + WS_TT);
    for (int i = tid; i < NITER; i += 768) sm.lp.tt[i] = wt[i];
  } else {
    if (tid == 0) {
      float t = 1.0f;
      for (int k = 0; k < NITER; ++k) {
        float tn = 0.5f * (1.0f + sqrtf(1.0f + 4.0f * t * t));
        float tt = (t - 1.0f) / tn;
        sm.lp.tt[k] = make_float2(tt, 1.0f + tt);
        t = tn;
      }
    }
  }
  __syncthreads();

  // ---------- swizzled LDS addresses (loop-invariant) ----------
  unsigned char* colb = &sm.lp.bounce[0][0] + cl * 384;
  const unsigned swz = (unsigned)((cl & 7) << 4);
  unsigned char* rdA[6];
  #pragma unroll
  for (int kt = 0; kt < 6; ++kt)
    rdA[kt] = colb + (((unsigned)(kt * 64 + hi * 16)) ^ swz);
  unsigned char* wrA = colb + (((unsigned)(wv * 32 + hi * 8)) ^ swz);

  // ---------- FISTA main loop ----------
  // p tracks A*xe + DtY (xe = running sum of bf16-quantized increments, error feedback).
  // u = (1+tt)p_k - tt p_{k-1}; xn = shrink(u); dq = bf16(xn - xe); xe += dq;
  // p_{k+1} = p_k + (Ah+Al)*dq  (split-precision bf16 MFMA pair).
  auto step = [&](f32x4& PC, f32x4& PN, int it, int boff) {
    float2 t2 = sm.lp.tt[it];
    const float ttp = t2.x, c1 = t2.y;
    float dq_[4];
    #pragma unroll
    for (int q = 0; q < 4; ++q) {
      float u  = c1 * PC[q] - ttp * PN[q];
      float aa = fmaxf(fabsf(u) - lambd, 0.0f);
      float xn = __builtin_copysignf(aa, u);
      dq_[q] = xn - xe[q];
    }
    unsigned w0 = cvt_pk_bf16(dq_[0], dq_[1]);
    unsigned w1 = cvt_pk_bf16(dq_[2], dq_[3]);
    xe[0] += ubit(w0 << 16);
    xe[1] += ubit(w0 & 0xffff0000u);
    xe[2] += ubit(w1 << 16);
    xe[3] += ubit(w1 & 0xffff0000u);
    *reinterpret_cast<uint2*>(wrA + boff) = make_uint2(w0, w1);
    __syncthreads();   // d visible; double-buffer -> 1 barrier/step
    bf16x8 bh[6];
    #pragma unroll
    for (int kt = 0; kt < 6; ++kt)
      bh[kt] = *reinterpret_cast<const bf16x8*>(rdA[kt] + boff);
    f32x4 acc = PC;
    #pragma unroll
    for (int kt = 0; kt < 6; ++kt) {
      acc = __builtin_amdgcn_mfma_f32_16x16x32_bf16(Ah[kt], bh[kt], acc, 0, 0, 0);
      acc = __builtin_amdgcn_mfma_f32_16x16x32_bf16(Al[kt], bh[kt], acc, 0, 0, 0);
    }
    PN = acc;          // p_{k+1}
  };

  #pragma unroll 1
  for (int j = 0; j < NITER / 2; ++j) {
    step(P0, P1, 2 * j, 0);
    step(P1, P0, 2 * j + 1, BUFB);
  }

  // ---------- store x (= xe) ----------
  float* op = out + (size_t)b * (161 * 16384) + p;
  #pragma unroll
  for (int q = 0; q < 4; ++q) {
    int r = wv * 16 + hi * 4 + q;
    if (r < 161) op[(size_t)r * 16384] = xe[q];
  }
}

extern "C" void kernel_launch(void* const* d_in, const int* in_sizes, int n_in,
                              void* d_out, int out_size, void* d_ws, size_t ws_size,
                              hipStream_t stream) {
  const float* X   = (const float*)d_in[0];
  const float* Drr = (const float*)d_in[1];
  const float* Dth = (const float*)d_in[2];
  float* out = (float*)d_out;
  (void)in_sizes; (void)n_in; (void)out_size;

  if (ws_size >= (size_t)WS_FLOATS * sizeof(float)) {
    float* ws = (float*)d_ws;
    prep_kernel<<<dim3(64), dim3(256), 0, stream>>>(Drr, Dth, ws);
    fista_kernel<1><<<dim3(4096), dim3(768), 0, stream>>>(X, Drr, Dth, out, ws);
  } else {
    fista_kernel<0><<<dim3(4096), dim3(768), 0, stream>>>(X, Drr, Dth, out, nullptr);
  }
}